// Round 9
// baseline (233.428 us; speedup 1.0000x reference)
//
#include <hip/hip_runtime.h>
#include <hip/hip_bf16.h>

// Problem constants
#define B 2048
#define D 1024
#define H 64
#define DOUT (D - 4)      // 1020
#define T 128             // chunks; chunk t anchored at dstart = 8t+4
#define DC 8              // dims per chunk (last chunk: 4)

typedef __attribute__((ext_vector_type(8))) short short8;
typedef __attribute__((ext_vector_type(4))) float f32x4;

// Workspace layout (float slots):
//   S   : T*B*H f16 = 16,777,216 halfs -> 8,388,608 float slots
//   VbP : D*2*64 uint4 (bf16 A-frags, 12-row-padded V) -> 524,288 float slots
//   Wth : D*H f16 -> 32,768 float slots
#define WS_S  0
#define WS_VB (T * B * H / 2)
#define WS_WT (WS_VB + D * 2 * 64 * 4)

__device__ __forceinline__ unsigned short f2h_u(float f) {
    union { _Float16 h; unsigned short u; } v; v.h = (_Float16)f; return v.u;
}
__device__ __forceinline__ float h2f_u(unsigned short s) {
    union { unsigned short u; _Float16 h; } v; v.u = s; return (float)v.h;
}
__device__ __forceinline__ unsigned short f2bf(float f) {
    union { float f; unsigned int u; } v; v.f = f;
    unsigned int r = (v.u + 0x7FFFu + ((v.u >> 16) & 1u)) >> 16;  // RNE
    return (unsigned short)r;
}
__device__ __forceinline__ unsigned cvtpk_bf16(float lo, float hi) {
    unsigned d;
    asm("v_cvt_pk_bf16_f32 %0, %1, %2" : "=v"(d) : "v"(lo), "v"(hi));
    return d;
}

union U8 { unsigned u[4]; short8 s; };

// ---------------------------------------------------------------------------
// Prep (fused): blocks 0..511 pack V into MFMA A-frag layout (bf16, 12 padded
// m-rows; m: 0-2 Vmean, 4-6 Vstd, 8-10 Valpha, else 0):
//   VbP[(d*2+ks)*64 + l] = 8 bf16: j -> V[d][h=ks*32+(l>>4)*8+j][m(l&15)]
// Blocks 512..527: transpose W[H][D] -> Wth[D][H] (f16) via LDS tile.
// ---------------------------------------------------------------------------
__global__ __launch_bounds__(256) void k_prep(const float* __restrict__ Vm,
                                              const float* __restrict__ Va,
                                              const float* __restrict__ Vs,
                                              const float* __restrict__ W,
                                              uint4* __restrict__ VbP,
                                              unsigned short* __restrict__ Wth) {
    __shared__ float tile[64][65];
    const int tid = threadIdx.x;
    const int bid = blockIdx.x;
    if (bid < 512) {
        const int idx = bid * 256 + tid;          // (d*2+ks)*64 + l
        const int l   = idx & 63;
        const int ks  = (idx >> 6) & 1;
        const int d   = idx >> 7;
        const int m   = l & 15;
        const int h0  = ks * 32 + (l >> 4) * 8;

        const float* src = nullptr;
        int k = 0;
        if (m < 3)                 { src = Vm; k = m; }
        else if (m >= 4 && m < 7)  { src = Vs; k = m - 4; }
        else if (m >= 8 && m < 11) { src = Va; k = m - 8; }

        unsigned u[4] = {0u, 0u, 0u, 0u};
        if (src) {
#pragma unroll
            for (int i = 0; i < 4; ++i) {
                unsigned short lo = f2bf(src[((size_t)d * H + h0 + 2 * i) * 3 + k]);
                unsigned short hi = f2bf(src[((size_t)d * H + h0 + 2 * i + 1) * 3 + k]);
                u[i] = ((unsigned)hi << 16) | lo;
            }
        }
        VbP[idx] = make_uint4(u[0], u[1], u[2], u[3]);
    } else {
        const int d0 = (bid - 512) * 64;
        const int tx = tid & 63;
        const int ty = tid >> 6;
#pragma unroll
        for (int r = 0; r < 64; r += 4)
            tile[r + ty][tx] = W[(size_t)(r + ty) * D + d0 + tx];   // tile[h][dl]
        __syncthreads();
#pragma unroll
        for (int r = 0; r < 64; r += 4)
            Wth[(size_t)(d0 + r + ty) * H + tx] = f2h_u(tile[tx][r + ty]);
    }
}

// ---------------------------------------------------------------------------
// Prefix: one wave per b (lane = h). No LDS, no barriers. W from Wth (f16,
// coalesced per-d 128B/wave, L2-resident); x broadcast via __shfl (readlane).
// Emit f16 checkpoint S[t][b][h] = c + sum_{j<8t+4} at d = 8t+4.
// grid (B/4), block 256 (4 waves = 4 b).
// ---------------------------------------------------------------------------
__global__ __launch_bounds__(256) void k_prefix(const float* __restrict__ x,
                                                const unsigned short* __restrict__ Wth,
                                                const float* __restrict__ cvec,
                                                unsigned short* __restrict__ S) {
    const int lane = threadIdx.x & 63;  // h
    const int w    = threadIdx.x >> 6;
    const int b    = blockIdx.x * 4 + w;

    float run = cvec[lane];
    const float* xr = x + (size_t)b * D;
    float xv = xr[lane];                // chunk 0 x, preloaded
    for (int c = 0; c < 16; ++c) {
        const float xnext = (c < 15) ? xr[(c + 1) * 64 + lane] : 0.f;
#pragma unroll
        for (int j = 0; j < 64; ++j) {
            const int d = c * 64 + j;
            if ((d & 7) == 4)           // d = 8t+4 -> t = d>>3
                S[((size_t)(d >> 3) * B + b) * H + lane] = f2h_u(run);
            const float wv = h2f_u(Wth[(size_t)d * H + lane]);
            run = fmaf(__shfl(xv, j), wv, run);
        }
        xv = xnext;
    }
}

// ---------------------------------------------------------------------------
// Main (MFMA): block = 4 waves = 256 b at chunk t (dims 8t+4..+11; last: 4).
// Per wave: 64 b via 4 n-tiles (bt). State a[4bt][2ks][8j] f32 in regs.
// Per d: B-frag = relu(a)->bf16 (cvt_pk), A-frag = V from LDS, bias as C-in,
// 8 MFMA, per-lane epilogue by quarter, 48B-aligned float4 flush per 4 dims.
// grid (B/256, T), block 256, 4 blocks/CU.
// ---------------------------------------------------------------------------
__global__ __launch_bounds__(256, 4) void k_main(const float* __restrict__ x,
                                                 const unsigned short* __restrict__ Wth,
                                                 const unsigned short* __restrict__ S,
                                                 const uint4* __restrict__ VbP,
                                                 const float* __restrict__ bm,
                                                 const float* __restrict__ ba,
                                                 const float* __restrict__ bs,
                                                 float* __restrict__ out) {
    __shared__ short8 vbsh[DC][2][64];   // 16 KB  A-frags
    __shared__ float  wshf[DC][64];      //  2 KB  W[d][h] f32
    __shared__ float  xsf[DC][256];      //  8 KB  x[d][b_local]
    __shared__ float  bshf[DC][16];      // 0.5 KB bias by m-row

    const int tid    = threadIdx.x;
    const int lane   = tid & 63;
    const int w      = tid >> 6;
    const int t      = blockIdx.y;
    const int bx     = blockIdx.x;
    const int dstart = 8 * t + 4;
    const int dvalid = D - dstart;       // 8, except 4 at t=127
    const int r      = lane & 15;        // n within tile (b)
    const int qq     = lane >> 4;        // quarter -> m-row group / k-slice

    // ---- stage chunk ----
    {
        const uint4* vsrc = VbP + (size_t)dstart * 128;
        uint4* vdst = (uint4*)vbsh;
#pragma unroll
        for (int q = 0; q < 4; ++q) {
            const int j = q * 256 + tid;
            if (j < dvalid * 128) vdst[j] = vsrc[j];
        }
        {   // W: dvalid*64 f16 = dvalid*32 dwords, one dword/thread
            const unsigned* wsrc = (const unsigned*)(Wth + (size_t)dstart * H);
            if (tid < dvalid * 32) {
                const unsigned u = wsrc[tid];
                const int dl = tid >> 5, h = (tid & 31) * 2;
                wshf[dl][h]     = h2f_u((unsigned short)(u & 0xffff));
                wshf[dl][h + 1] = h2f_u((unsigned short)(u >> 16));
            }
        }
        {   // x: thread = local b, 2x float4 row read, transpose to [d][b]
            const float* xr2 = x + (size_t)(bx * 256 + tid) * D + dstart;
#pragma unroll
            for (int part = 0; part < 2; ++part) {
                if (part * 4 < dvalid) {
                    float4 v = *(const float4*)(xr2 + part * 4);
                    xsf[part * 4 + 0][tid] = v.x;
                    xsf[part * 4 + 1][tid] = v.y;
                    xsf[part * 4 + 2][tid] = v.z;
                    xsf[part * 4 + 3][tid] = v.w;
                }
            }
        }
        {   // bias: thread -> (dl, m)
            if (tid < DC * 16) {
                const int dl = tid >> 4, m = tid & 15;
                const int d = dstart + dl;
                float v = 0.f;
                if (d < D) {
                    if (m < 3)                 v = bm[(size_t)d * 3 + m];
                    else if (m >= 4 && m < 7)  v = bs[(size_t)d * 3 + m - 4];
                    else if (m >= 8 && m < 11) v = ba[(size_t)d * 3 + m - 8];
                }
                bshf[dl][m] = v;
            }
        }
    }

    // ---- load f16 checkpoints into B-frag-layout state a[bt][ks][j] ----
    float a_[4][2][8];
#pragma unroll
    for (int bt = 0; bt < 4; ++bt) {
#pragma unroll
        for (int ks = 0; ks < 2; ++ks) {
            const unsigned short* sp =
                S + ((size_t)t * B + bx * 256 + w * 64 + bt * 16 + r) * H + ks * 32 + qq * 8;
            uint4 u = *(const uint4*)sp;
            a_[bt][ks][0] = h2f_u((unsigned short)(u.x & 0xffff));
            a_[bt][ks][1] = h2f_u((unsigned short)(u.x >> 16));
            a_[bt][ks][2] = h2f_u((unsigned short)(u.y & 0xffff));
            a_[bt][ks][3] = h2f_u((unsigned short)(u.y >> 16));
            a_[bt][ks][4] = h2f_u((unsigned short)(u.z & 0xffff));
            a_[bt][ks][5] = h2f_u((unsigned short)(u.z >> 16));
            a_[bt][ks][6] = h2f_u((unsigned short)(u.w & 0xffff));
            a_[bt][ks][7] = h2f_u((unsigned short)(u.w >> 16));
        }
    }
    __syncthreads();

    const int nq = (t == T - 1) ? 1 : 2;
    for (int qd = 0; qd < nq; ++qd) {
        float buf[4][12];
#pragma unroll
        for (int d4 = 0; d4 < 4; ++d4) {
            const int dl = qd * 4 + d4;

            // B-frags: relu + pack to bf16
            U8 bf[4][2];
#pragma unroll
            for (int bt = 0; bt < 4; ++bt)
#pragma unroll
                for (int ks = 0; ks < 2; ++ks)
#pragma unroll
                    for (int i = 0; i < 4; ++i)
                        bf[bt][ks].u[i] = cvtpk_bf16(fmaxf(a_[bt][ks][2 * i], 0.f),
                                                     fmaxf(a_[bt][ks][2 * i + 1], 0.f));

            // A-frags + bias C-in
            short8 A0 = vbsh[dl][0][lane];
            short8 A1 = vbsh[dl][1][lane];
            f32x4 bias4 = ((const f32x4*)&bshf[dl][0])[qq];

            // 8 MFMA: 4 bt x 2 chained K-steps
            f32x4 acc[4];
#pragma unroll
            for (int bt = 0; bt < 4; ++bt) {
                acc[bt] = __builtin_amdgcn_mfma_f32_16x16x32_bf16(A0, bf[bt][0].s, bias4, 0, 0, 0);
                acc[bt] = __builtin_amdgcn_mfma_f32_16x16x32_bf16(A1, bf[bt][1].s, acc[bt], 0, 0, 0);
            }

            // epilogue per lane-quarter: q0 mean (raw), q1 std, q2 alpha, q3 idle
#pragma unroll
            for (int bt = 0; bt < 4; ++bt) {
                float z0 = acc[bt][0], z1 = acc[bt][1], z2 = acc[bt][2];
                float o0 = z0, o1 = z1, o2 = z2;
                if (qq == 1) {
                    o0 = 2.f * __builtin_amdgcn_rcpf(1.f + __expf(-z0)) + 0.6f;
                    o1 = 2.f * __builtin_amdgcn_rcpf(1.f + __expf(-z1)) + 0.6f;
                    o2 = 2.f * __builtin_amdgcn_rcpf(1.f + __expf(-z2)) + 0.6f;
                } else if (qq == 2) {
                    float mx = fmaxf(z0, fmaxf(z1, z2));
                    float e0 = __expf(z0 - mx);
                    float e1 = __expf(z1 - mx);
                    float e2 = __expf(z2 - mx);
                    float inv = __builtin_amdgcn_rcpf(e0 + e1 + e2);
                    o0 = e0 * inv; o1 = e1 * inv; o2 = e2 * inv;
                }
                buf[bt][d4 * 3 + 0] = o0;
                buf[bt][d4 * 3 + 1] = o1;
                buf[bt][d4 * 3 + 2] = o2;
            }

            // a-update: a[bt][ks][j] += x[b(bt)] * W[h(ks,qq,j)]
            float4 w0a = *(const float4*)&wshf[dl][qq * 8];
            float4 w0b = *(const float4*)&wshf[dl][qq * 8 + 4];
            float4 w1a = *(const float4*)&wshf[dl][32 + qq * 8];
            float4 w1b = *(const float4*)&wshf[dl][32 + qq * 8 + 4];
#pragma unroll
            for (int bt = 0; bt < 4; ++bt) {
                const float xv = xsf[dl][w * 64 + bt * 16 + r];
                a_[bt][0][0] = fmaf(xv, w0a.x, a_[bt][0][0]);
                a_[bt][0][1] = fmaf(xv, w0a.y, a_[bt][0][1]);
                a_[bt][0][2] = fmaf(xv, w0a.z, a_[bt][0][2]);
                a_[bt][0][3] = fmaf(xv, w0a.w, a_[bt][0][3]);
                a_[bt][0][4] = fmaf(xv, w0b.x, a_[bt][0][4]);
                a_[bt][0][5] = fmaf(xv, w0b.y, a_[bt][0][5]);
                a_[bt][0][6] = fmaf(xv, w0b.z, a_[bt][0][6]);
                a_[bt][0][7] = fmaf(xv, w0b.w, a_[bt][0][7]);
                a_[bt][1][0] = fmaf(xv, w1a.x, a_[bt][1][0]);
                a_[bt][1][1] = fmaf(xv, w1a.y, a_[bt][1][1]);
                a_[bt][1][2] = fmaf(xv, w1a.z, a_[bt][1][2]);
                a_[bt][1][3] = fmaf(xv, w1a.w, a_[bt][1][3]);
                a_[bt][1][4] = fmaf(xv, w1b.x, a_[bt][1][4]);
                a_[bt][1][5] = fmaf(xv, w1b.y, a_[bt][1][5]);
                a_[bt][1][6] = fmaf(xv, w1b.z, a_[bt][1][6]);
                a_[bt][1][7] = fmaf(xv, w1b.w, a_[bt][1][7]);
            }
        }

        // flush: 48B-aligned float4 runs; i0 = 8t + 4qd
        if (qq < 3) {
            float* ob = out + (size_t)qq * ((size_t)B * DOUT * 3);
            const size_t ioff = (size_t)(8 * t + 4 * qd) * 3;
#pragma unroll
            for (int bt = 0; bt < 4; ++bt) {
                float* p = ob + (size_t)(bx * 256 + w * 64 + bt * 16 + r) * (DOUT * 3) + ioff;
                *(float4*)(p + 0) = make_float4(buf[bt][0], buf[bt][1], buf[bt][2], buf[bt][3]);
                *(float4*)(p + 4) = make_float4(buf[bt][4], buf[bt][5], buf[bt][6], buf[bt][7]);
                *(float4*)(p + 8) = make_float4(buf[bt][8], buf[bt][9], buf[bt][10], buf[bt][11]);
            }
        }
    }
}

// ---------------------------------------------------------------------------
extern "C" void kernel_launch(void* const* d_in, const int* in_sizes, int n_in,
                              void* d_out, int out_size, void* d_ws, size_t ws_size,
                              hipStream_t stream) {
    const float* x  = (const float*)d_in[0];   // [B, D]
    const float* W  = (const float*)d_in[1];   // [H, D]
    const float* c  = (const float*)d_in[2];   // [1, H]
    const float* Vm = (const float*)d_in[3];   // [D, H, K]
    const float* Va = (const float*)d_in[4];   // [D, H, K]
    const float* Vs = (const float*)d_in[5];   // [D, H, K]
    const float* bm = (const float*)d_in[6];   // [D, K]
    const float* ba = (const float*)d_in[7];   // [D, K]
    const float* bs = (const float*)d_in[8];   // [D, K]
    float* out = (float*)d_out;

    float* wsf = (float*)d_ws;
    unsigned short* S = (unsigned short*)(wsf + WS_S);
    uint4* VbP = (uint4*)(wsf + WS_VB);
    unsigned short* Wth = (unsigned short*)(wsf + WS_WT);

    k_prep<<<dim3(512 + 16), dim3(256), 0, stream>>>(Vm, Va, Vs, W, VbP, Wth);
    k_prefix<<<dim3(B / 4), dim3(256), 0, stream>>>(x, Wth, c, S);
    k_main<<<dim3(B / 256, T), dim3(256), 0, stream>>>(x, Wth, S, VbP, bm, ba, bs, out);
}

// Round 10
// 193.692 us; speedup vs baseline: 1.2052x; 1.2052x over previous
//
#include <hip/hip_runtime.h>
#include <hip/hip_bf16.h>

// Problem constants
#define B 2048
#define D 1024
#define H 64
#define DOUT (D - 4)      // 1020
#define T 64              // chunks; chunk t anchored at dstart = 16t+4
#define DC 16             // dims per chunk (last chunk: 12)

typedef __attribute__((ext_vector_type(8))) short short8;
typedef __attribute__((ext_vector_type(4))) float f32x4;

// Workspace layout (float slots):
//   S   : T*B*H f16 = 8,388,608 halfs -> 4,194,304 float slots
//   VbP : D*2*64 uint4 (bf16 A-frags, 12-row-padded V) -> 524,288 float slots
//   Wth : D*H f16 -> 32,768 float slots
#define WS_S  0
#define WS_VB (T * B * H / 2)
#define WS_WT (WS_VB + D * 2 * 64 * 4)

__device__ __forceinline__ unsigned short f2h_u(float f) {
    union { _Float16 h; unsigned short u; } v; v.h = (_Float16)f; return v.u;
}
__device__ __forceinline__ float h2f_u(unsigned short s) {
    union { unsigned short u; _Float16 h; } v; v.u = s; return (float)v.h;
}
__device__ __forceinline__ unsigned short f2bf(float f) {
    union { float f; unsigned int u; } v; v.f = f;
    unsigned int r = (v.u + 0x7FFFu + ((v.u >> 16) & 1u)) >> 16;  // RNE
    return (unsigned short)r;
}
__device__ __forceinline__ unsigned cvtpk_bf16(float lo, float hi) {
    unsigned d;
    asm("v_cvt_pk_bf16_f32 %0, %1, %2" : "=v"(d) : "v"(lo), "v"(hi));
    return d;
}

union U8 { unsigned u[4]; short8 s; };
union U8Q { uint4 q; short8 s; };

// ---------------------------------------------------------------------------
// Prep (fused):
//  blocks 0..255: pack V into MFMA A-frag layout (bf16, 12 padded m-rows;
//   m: 0-2 Vmean, 4-6 Vstd, 8-10 Valpha, else 0). 4 d per block, fully
//   coalesced global reads staged in LDS, frag gather from LDS.
//   VbP[(d*2+ks)*64 + l] = 8 bf16: j -> V[d][h=ks*32+(l>>4)*8+j][m(l&15)]
//  blocks 256..271: transpose W[H][D] -> Wth[D][H] (f16) via LDS tile.
// ---------------------------------------------------------------------------
__global__ __launch_bounds__(256) void k_prep(const float* __restrict__ Vm,
                                              const float* __restrict__ Va,
                                              const float* __restrict__ Vs,
                                              const float* __restrict__ W,
                                              uint4* __restrict__ VbP,
                                              unsigned short* __restrict__ Wth) {
    __shared__ float vl[4][3][192];     // 9 KB: 4 d x {mean,std,alpha} x (h*3+k)
    __shared__ float tile[64][65];
    const int tid = threadIdx.x;
    const int bid = blockIdx.x;
    if (bid < 256) {
        const int d0 = bid * 4;
        // coalesced load: 4 d x 3 arrays x 192 floats = 2304
#pragma unroll
        for (int q = 0; q < 9; ++q) {
            const int j = q * 256 + tid;
            if (j < 2304) {
                const int dl  = j / 576;
                const int rem = j % 576;
                const int arr = rem / 192;
                const int off = rem % 192;
                const float* src = (arr == 0) ? Vm : (arr == 1) ? Vs : Va;
                vl[dl][arr][off] = src[(size_t)(d0 + dl) * 192 + off];
            }
        }
        __syncthreads();
        // write 4 d x 128 frags = 512 uint4
#pragma unroll
        for (int q = 0; q < 2; ++q) {
            const int j  = q * 256 + tid;     // dl*128 + ks*64 + l
            const int dl = j >> 7;
            const int ks = (j >> 6) & 1;
            const int l  = j & 63;
            const int m  = l & 15;
            const int h0 = ks * 32 + (l >> 4) * 8;
            int arr = -1, k = 0;
            if (m < 3)                 { arr = 0; k = m; }
            else if (m >= 4 && m < 7)  { arr = 1; k = m - 4; }
            else if (m >= 8 && m < 11) { arr = 2; k = m - 8; }
            unsigned u[4] = {0u, 0u, 0u, 0u};
            if (arr >= 0) {
#pragma unroll
                for (int i = 0; i < 4; ++i) {
                    unsigned short lo = f2bf(vl[dl][arr][(h0 + 2 * i) * 3 + k]);
                    unsigned short hi = f2bf(vl[dl][arr][(h0 + 2 * i + 1) * 3 + k]);
                    u[i] = ((unsigned)hi << 16) | lo;
                }
            }
            VbP[((size_t)(d0 + dl) * 2 + ks) * 64 + l] = make_uint4(u[0], u[1], u[2], u[3]);
        }
    } else {
        const int d0 = (bid - 256) * 64;
        const int tx = tid & 63;
        const int ty = tid >> 6;
#pragma unroll
        for (int r = 0; r < 64; r += 4)
            tile[r + ty][tx] = W[(size_t)(r + ty) * D + d0 + tx];   // tile[h][dl]
        __syncthreads();
#pragma unroll
        for (int r = 0; r < 64; r += 4)
            Wth[(size_t)(d0 + r + ty) * H + tx] = f2h_u(tile[tx][r + ty]);
    }
}

// ---------------------------------------------------------------------------
// Prefix: one wave per b (lane = h). No LDS, no barriers. W from Wth (f16,
// coalesced 128B/wave/d, L2-resident); x broadcast via __shfl (readlane).
// Emit f16 checkpoint S[t][b][h] = c + sum_{j<16t+4} at d = 16t+4.
// grid (B/4), block 256 (4 waves = 4 b).
// ---------------------------------------------------------------------------
__global__ __launch_bounds__(256) void k_prefix(const float* __restrict__ x,
                                                const unsigned short* __restrict__ Wth,
                                                const float* __restrict__ cvec,
                                                unsigned short* __restrict__ S) {
    const int lane = threadIdx.x & 63;  // h
    const int w    = threadIdx.x >> 6;
    const int b    = blockIdx.x * 4 + w;

    float run = cvec[lane];
    const float* xr = x + (size_t)b * D;
    float xv = xr[lane];                // chunk 0 x, preloaded
    for (int c = 0; c < 16; ++c) {
        const float xnext = (c < 15) ? xr[(c + 1) * 64 + lane] : 0.f;
#pragma unroll
        for (int j = 0; j < 64; ++j) {
            const int d = c * 64 + j;
            if ((d & 15) == 4)          // d = 16t+4 -> t = d>>4
                S[((size_t)(d >> 4) * B + b) * H + lane] = f2h_u(run);
            const float wv = h2f_u(Wth[(size_t)d * H + lane]);
            run = fmaf(__shfl(xv, j), wv, run);
        }
        xv = xnext;
    }
}

// ---------------------------------------------------------------------------
// Main (MFMA): block = 4 waves = 128 b at chunk t (dims 16t+4..+19; last 12).
// Per wave: 32 b via 2 n-tiles (bt). State a[2bt][2ks][8j] f32 in regs (~95
// live VGPRs, no spill). A-frags read per-lane from global VbP (L2-resident,
// coalesced 16B/lane) -- no LDS stage, LDS = 13 KB. Bias as MFMA C-in.
// grid (B/128, T) = 1024 blocks = 4 blocks/CU, 16 waves/CU.
// ---------------------------------------------------------------------------
__global__ __launch_bounds__(256, 2) void k_main(const float* __restrict__ x,
                                                 const unsigned short* __restrict__ Wth,
                                                 const unsigned short* __restrict__ S,
                                                 const uint4* __restrict__ VbP,
                                                 const float* __restrict__ bm,
                                                 const float* __restrict__ ba,
                                                 const float* __restrict__ bs,
                                                 float* __restrict__ out) {
    __shared__ float wshf[DC][64];      //  4 KB  W[d][h] f32
    __shared__ float xsf[DC][128];      //  8 KB  x[d][b_local]
    __shared__ float bshf[DC][16];      //  1 KB  bias by m-row

    const int tid    = threadIdx.x;
    const int lane   = tid & 63;
    const int w      = tid >> 6;
    const int t      = blockIdx.y;
    const int bx     = blockIdx.x;
    const int dstart = 16 * t + 4;
    const int dvalid = D - dstart;       // 16, except 12 at t=63
    const int r      = lane & 15;        // n within tile (b)
    const int qq     = lane >> 4;        // quarter -> m-row group / k-slice

    // ---- stage chunk ----
    {
        {   // W: dvalid*64 f16 = dvalid*32 dwords <= 512; 256 threads x 2
            const unsigned* wsrc = (const unsigned*)(Wth + (size_t)dstart * H);
#pragma unroll
            for (int q = 0; q < 2; ++q) {
                const int idx = q * 256 + tid;
                if (idx < dvalid * 32) {
                    const unsigned u = wsrc[idx];
                    const int dl = idx >> 5, h = (idx & 31) * 2;
                    wshf[dl][h]     = h2f_u((unsigned short)(u & 0xffff));
                    wshf[dl][h + 1] = h2f_u((unsigned short)(u >> 16));
                }
            }
        }
        {   // x: 128 rows x dvalid floats; thread j -> (row j>>2, part j&3)
#pragma unroll
            for (int q = 0; q < 2; ++q) {
                const int j = q * 256 + tid;
                const int row = j >> 2, part = j & 3;
                if (part * 4 < dvalid) {
                    float4 v = *(const float4*)(x + (size_t)(bx * 128 + row) * D + dstart + part * 4);
                    xsf[part * 4 + 0][row] = v.x;
                    xsf[part * 4 + 1][row] = v.y;
                    xsf[part * 4 + 2][row] = v.z;
                    xsf[part * 4 + 3][row] = v.w;
                }
            }
        }
        {   // bias: thread -> (dl, m)
            const int dl = tid >> 4, m = tid & 15;
            const int d = dstart + dl;
            float v = 0.f;
            if (d < D) {
                if (m < 3)                 v = bm[(size_t)d * 3 + m];
                else if (m >= 4 && m < 7)  v = bs[(size_t)d * 3 + m - 4];
                else if (m >= 8 && m < 11) v = ba[(size_t)d * 3 + m - 8];
            }
            bshf[dl][m] = v;
        }
    }

    // ---- load f16 checkpoints into B-frag-layout state a[bt][ks][j] ----
    float a_[2][2][8];
#pragma unroll
    for (int bt = 0; bt < 2; ++bt) {
#pragma unroll
        for (int ks = 0; ks < 2; ++ks) {
            const unsigned short* sp =
                S + ((size_t)t * B + bx * 128 + w * 32 + bt * 16 + r) * H + ks * 32 + qq * 8;
            uint4 u = *(const uint4*)sp;
            a_[bt][ks][0] = h2f_u((unsigned short)(u.x & 0xffff));
            a_[bt][ks][1] = h2f_u((unsigned short)(u.x >> 16));
            a_[bt][ks][2] = h2f_u((unsigned short)(u.y & 0xffff));
            a_[bt][ks][3] = h2f_u((unsigned short)(u.y >> 16));
            a_[bt][ks][4] = h2f_u((unsigned short)(u.z & 0xffff));
            a_[bt][ks][5] = h2f_u((unsigned short)(u.z >> 16));
            a_[bt][ks][6] = h2f_u((unsigned short)(u.w & 0xffff));
            a_[bt][ks][7] = h2f_u((unsigned short)(u.w >> 16));
        }
    }
    __syncthreads();

    const int nq = (t == T - 1) ? 3 : 4;
    for (int qd = 0; qd < nq; ++qd) {
        float buf[2][12];
#pragma unroll
        for (int d4 = 0; d4 < 4; ++d4) {
            const int dl = qd * 4 + d4;
            const int d  = dstart + dl;

            // A-frags from global (L2-resident, 16B/lane coalesced) -- issue early
            U8Q A0, A1;
            A0.q = VbP[((size_t)d * 2 + 0) * 64 + lane];
            A1.q = VbP[((size_t)d * 2 + 1) * 64 + lane];

            // B-frags: relu + pack to bf16
            U8 bf[2][2];
#pragma unroll
            for (int bt = 0; bt < 2; ++bt)
#pragma unroll
                for (int ks = 0; ks < 2; ++ks)
#pragma unroll
                    for (int i = 0; i < 4; ++i)
                        bf[bt][ks].u[i] = cvtpk_bf16(fmaxf(a_[bt][ks][2 * i], 0.f),
                                                     fmaxf(a_[bt][ks][2 * i + 1], 0.f));

            f32x4 bias4 = ((const f32x4*)&bshf[dl][0])[qq];

            // 4 MFMA: 2 bt x 2 chained K-steps
            f32x4 acc[2];
#pragma unroll
            for (int bt = 0; bt < 2; ++bt) {
                acc[bt] = __builtin_amdgcn_mfma_f32_16x16x32_bf16(A0.s, bf[bt][0].s, bias4, 0, 0, 0);
                acc[bt] = __builtin_amdgcn_mfma_f32_16x16x32_bf16(A1.s, bf[bt][1].s, acc[bt], 0, 0, 0);
            }

            // epilogue per lane-quarter: q0 mean (raw), q1 std, q2 alpha, q3 idle
#pragma unroll
            for (int bt = 0; bt < 2; ++bt) {
                float z0 = acc[bt][0], z1 = acc[bt][1], z2 = acc[bt][2];
                float o0 = z0, o1 = z1, o2 = z2;
                if (qq == 1) {
                    o0 = 2.f * __builtin_amdgcn_rcpf(1.f + __expf(-z0)) + 0.6f;
                    o1 = 2.f * __builtin_amdgcn_rcpf(1.f + __expf(-z1)) + 0.6f;
                    o2 = 2.f * __builtin_amdgcn_rcpf(1.f + __expf(-z2)) + 0.6f;
                } else if (qq == 2) {
                    float mx = fmaxf(z0, fmaxf(z1, z2));
                    float e0 = __expf(z0 - mx);
                    float e1 = __expf(z1 - mx);
                    float e2 = __expf(z2 - mx);
                    float inv = __builtin_amdgcn_rcpf(e0 + e1 + e2);
                    o0 = e0 * inv; o1 = e1 * inv; o2 = e2 * inv;
                }
                buf[bt][d4 * 3 + 0] = o0;
                buf[bt][d4 * 3 + 1] = o1;
                buf[bt][d4 * 3 + 2] = o2;
            }

            // a-update: a[bt][ks][j] += x[b(bt)] * W[h(ks,qq,j)]
            float4 w0a = *(const float4*)&wshf[dl][qq * 8];
            float4 w0b = *(const float4*)&wshf[dl][qq * 8 + 4];
            float4 w1a = *(const float4*)&wshf[dl][32 + qq * 8];
            float4 w1b = *(const float4*)&wshf[dl][32 + qq * 8 + 4];
#pragma unroll
            for (int bt = 0; bt < 2; ++bt) {
                const float xv = xsf[dl][w * 32 + bt * 16 + r];
                a_[bt][0][0] = fmaf(xv, w0a.x, a_[bt][0][0]);
                a_[bt][0][1] = fmaf(xv, w0a.y, a_[bt][0][1]);
                a_[bt][0][2] = fmaf(xv, w0a.z, a_[bt][0][2]);
                a_[bt][0][3] = fmaf(xv, w0a.w, a_[bt][0][3]);
                a_[bt][0][4] = fmaf(xv, w0b.x, a_[bt][0][4]);
                a_[bt][0][5] = fmaf(xv, w0b.y, a_[bt][0][5]);
                a_[bt][0][6] = fmaf(xv, w0b.z, a_[bt][0][6]);
                a_[bt][0][7] = fmaf(xv, w0b.w, a_[bt][0][7]);
                a_[bt][1][0] = fmaf(xv, w1a.x, a_[bt][1][0]);
                a_[bt][1][1] = fmaf(xv, w1a.y, a_[bt][1][1]);
                a_[bt][1][2] = fmaf(xv, w1a.z, a_[bt][1][2]);
                a_[bt][1][3] = fmaf(xv, w1a.w, a_[bt][1][3]);
                a_[bt][1][4] = fmaf(xv, w1b.x, a_[bt][1][4]);
                a_[bt][1][5] = fmaf(xv, w1b.y, a_[bt][1][5]);
                a_[bt][1][6] = fmaf(xv, w1b.z, a_[bt][1][6]);
                a_[bt][1][7] = fmaf(xv, w1b.w, a_[bt][1][7]);
            }
        }

        // flush: 48B-aligned float4 runs; i0 = 16t + 4qd
        if (qq < 3) {
            float* ob = out + (size_t)qq * ((size_t)B * DOUT * 3);
            const size_t ioff = (size_t)(16 * t + 4 * qd) * 3;
#pragma unroll
            for (int bt = 0; bt < 2; ++bt) {
                float* p = ob + (size_t)(bx * 128 + w * 32 + bt * 16 + r) * (DOUT * 3) + ioff;
                *(float4*)(p + 0) = make_float4(buf[bt][0], buf[bt][1], buf[bt][2], buf[bt][3]);
                *(float4*)(p + 4) = make_float4(buf[bt][4], buf[bt][5], buf[bt][6], buf[bt][7]);
                *(float4*)(p + 8) = make_float4(buf[bt][8], buf[bt][9], buf[bt][10], buf[bt][11]);
            }
        }
    }
}

// ---------------------------------------------------------------------------
extern "C" void kernel_launch(void* const* d_in, const int* in_sizes, int n_in,
                              void* d_out, int out_size, void* d_ws, size_t ws_size,
                              hipStream_t stream) {
    const float* x  = (const float*)d_in[0];   // [B, D]
    const float* W  = (const float*)d_in[1];   // [H, D]
    const float* c  = (const float*)d_in[2];   // [1, H]
    const float* Vm = (const float*)d_in[3];   // [D, H, K]
    const float* Va = (const float*)d_in[4];   // [D, H, K]
    const float* Vs = (const float*)d_in[5];   // [D, H, K]
    const float* bm = (const float*)d_in[6];   // [D, K]
    const float* ba = (const float*)d_in[7];   // [D, K]
    const float* bs = (const float*)d_in[8];   // [D, K]
    float* out = (float*)d_out;

    float* wsf = (float*)d_ws;
    unsigned short* S = (unsigned short*)(wsf + WS_S);
    uint4* VbP = (uint4*)(wsf + WS_VB);
    unsigned short* Wth = (unsigned short*)(wsf + WS_WT);

    k_prep<<<dim3(256 + 16), dim3(256), 0, stream>>>(Vm, Va, Vs, W, VbP, Wth);
    k_prefix<<<dim3(B / 4), dim3(256), 0, stream>>>(x, Wth, c, S);
    k_main<<<dim3(B / 128, T), dim3(256), 0, stream>>>(x, Wth, S, VbP, bm, ba, bs, out);
}

// Round 11
// 162.189 us; speedup vs baseline: 1.4392x; 1.1942x over previous
//
#include <hip/hip_runtime.h>
#include <hip/hip_bf16.h>

// Problem constants
#define B 2048
#define D 1024
#define H 64
#define DOUT (D - 4)      // 1020
#define T 128             // chunks; chunk t anchored at dstart = 8t+4
#define DC 8              // dims per chunk (last chunk: 4)

typedef __attribute__((ext_vector_type(8))) short short8;
typedef __attribute__((ext_vector_type(4))) float f32x4;

// Workspace layout (float slots):
//   S   : T*B*H f16 = 16,777,216 halfs -> 8,388,608 float slots (32MB)
//   VbP : D*2*64 uint4 (bf16 A-frags, 12-row-padded V) -> 524,288 float slots
//   Wth : D*H f16 -> 32,768 float slots
#define WS_S  0
#define WS_VB (T * B * H / 2)
#define WS_WT (WS_VB + D * 2 * 64 * 4)

__device__ __forceinline__ unsigned short f2h_u(float f) {
    union { _Float16 h; unsigned short u; } v; v.h = (_Float16)f; return v.u;
}
__device__ __forceinline__ float h2f_u(unsigned short s) {
    union { unsigned short u; _Float16 h; } v; v.u = s; return (float)v.h;
}
__device__ __forceinline__ unsigned short f2bf(float f) {
    union { float f; unsigned int u; } v; v.f = f;
    unsigned int r = (v.u + 0x7FFFu + ((v.u >> 16) & 1u)) >> 16;  // RNE
    return (unsigned short)r;
}
__device__ __forceinline__ unsigned cvtpk_bf16(float lo, float hi) {
    unsigned d;
    asm("v_cvt_pk_bf16_f32 %0, %1, %2" : "=v"(d) : "v"(lo), "v"(hi));
    return d;
}

union U8 { unsigned u[4]; short8 s; };

// ---------------------------------------------------------------------------
// Prep (fused):
//  blocks 0..255: pack V into MFMA A-frag layout (bf16, 12 padded m-rows;
//   m: 0-2 Vmean, 4-6 Vstd, 8-10 Valpha, else 0). 4 d per block, coalesced
//   global reads staged in LDS, frag gather from LDS.
//   VbP[(d*2+ks)*64 + l] = 8 bf16: j -> V[d][h=ks*32+(l>>4)*8+j][m(l&15)]
//  blocks 256..271: transpose W[H][D] -> Wth[D][H] (f16) via LDS tile.
// ---------------------------------------------------------------------------
__global__ __launch_bounds__(256) void k_prep(const float* __restrict__ Vm,
                                              const float* __restrict__ Va,
                                              const float* __restrict__ Vs,
                                              const float* __restrict__ W,
                                              uint4* __restrict__ VbP,
                                              unsigned short* __restrict__ Wth) {
    __shared__ float vl[4][3][192];     // 9 KB
    __shared__ float tile[64][65];
    const int tid = threadIdx.x;
    const int bid = blockIdx.x;
    if (bid < 256) {
        const int d0 = bid * 4;
#pragma unroll
        for (int q = 0; q < 9; ++q) {
            const int j = q * 256 + tid;
            if (j < 2304) {
                const int dl  = j / 576;
                const int rem = j % 576;
                const int arr = rem / 192;
                const int off = rem % 192;
                const float* src = (arr == 0) ? Vm : (arr == 1) ? Vs : Va;
                vl[dl][arr][off] = src[(size_t)(d0 + dl) * 192 + off];
            }
        }
        __syncthreads();
#pragma unroll
        for (int q = 0; q < 2; ++q) {
            const int j  = q * 256 + tid;     // dl*128 + ks*64 + l
            const int dl = j >> 7;
            const int ks = (j >> 6) & 1;
            const int l  = j & 63;
            const int m  = l & 15;
            const int h0 = ks * 32 + (l >> 4) * 8;
            int arr = -1, k = 0;
            if (m < 3)                 { arr = 0; k = m; }
            else if (m >= 4 && m < 7)  { arr = 1; k = m - 4; }
            else if (m >= 8 && m < 11) { arr = 2; k = m - 8; }
            unsigned u[4] = {0u, 0u, 0u, 0u};
            if (arr >= 0) {
#pragma unroll
                for (int i = 0; i < 4; ++i) {
                    unsigned short lo = f2bf(vl[dl][arr][(h0 + 2 * i) * 3 + k]);
                    unsigned short hi = f2bf(vl[dl][arr][(h0 + 2 * i + 1) * 3 + k]);
                    u[i] = ((unsigned)hi << 16) | lo;
                }
            }
            VbP[((size_t)(d0 + dl) * 2 + ks) * 64 + l] = make_uint4(u[0], u[1], u[2], u[3]);
        }
    } else {
        const int d0 = (bid - 256) * 64;
        const int tx = tid & 63;
        const int ty = tid >> 6;
#pragma unroll
        for (int r = 0; r < 64; r += 4)
            tile[r + ty][tx] = W[(size_t)(r + ty) * D + d0 + tx];   // tile[h][dl]
        __syncthreads();
#pragma unroll
        for (int r = 0; r < 64; r += 4)
            Wth[(size_t)(d0 + r + ty) * H + tx] = f2h_u(tile[tx][r + ty]);
    }
}

// ---------------------------------------------------------------------------
// Prefix (round-8 proven structure): wave per b (lane = h). W tiles (64 dims)
// staged in LDS [h][d] straight from W's native [h][d] layout; x broadcast via
// LDS. Emit f16 checkpoint S[t][b][h] = c + sum_{j<8t+4} at d = 8t+4.
// grid (B/8), block 512 (8 waves = 8 b).
// ---------------------------------------------------------------------------
__global__ __launch_bounds__(512) void k_prefix(const float* __restrict__ x,
                                                const float* __restrict__ W,
                                                const float* __restrict__ cvec,
                                                unsigned short* __restrict__ S) {
    __shared__ float wt[64 * 68];   // [h][d] padded
    __shared__ float xl[8 * 64];
    const int tid  = threadIdx.x;
    const int lane = tid & 63;      // h
    const int w    = tid >> 6;
    const int b    = blockIdx.x * 8 + w;

    float run = cvec[lane];
    for (int c = 0; c < 16; ++c) {
        __syncthreads();
        {   // stage W tile: thread -> (h = tid>>3, dc = (tid&7)*8), two float4
            const int h = tid >> 3, dc = (tid & 7) * 8;
            const float* src = W + (size_t)h * D + c * 64 + dc;
            float4 v0 = *(const float4*)src;
            float4 v1 = *(const float4*)(src + 4);
            float* dst = wt + h * 68 + dc;
            *(float4*)dst = v0;
            *(float4*)(dst + 4) = v1;
        }
        xl[w * 64 + lane] = x[(size_t)b * D + c * 64 + lane];
        __syncthreads();
#pragma unroll
        for (int dg = 0; dg < 16; ++dg) {
            if (dg & 1) {   // d_local = dg*4 in {4,12,...,60} -> t = 8c + (dg>>1)
                const int t = 8 * c + (dg >> 1);
                S[((size_t)t * B + b) * H + lane] = f2h_u(run);
            }
            float4 w4 = *(const float4*)(wt + lane * 68 + dg * 4);
            float4 x4 = *(const float4*)(xl + w * 64 + dg * 4);
            run = fmaf(x4.x, w4.x, run);
            run = fmaf(x4.y, w4.y, run);
            run = fmaf(x4.z, w4.z, run);
            run = fmaf(x4.w, w4.w, run);
        }
    }
}

// ---------------------------------------------------------------------------
// Main (MFMA): block = 4 waves = 128 b at chunk t (dims 8t+4..+11; last 4).
// Per wave: 32 b via 2 n-tiles (bt). State a[2bt][2ks][8j] f32 in regs.
// A-frags staged in LDS (ds_read_b128, no L2 round-trip in the d-loop).
// LDS = 22.5 KB -> up to 7 blocks/CU; grid (B/128, T) = 2048 blocks.
// ---------------------------------------------------------------------------
__global__ __launch_bounds__(256, 2) void k_main(const float* __restrict__ x,
                                                 const unsigned short* __restrict__ Wth,
                                                 const unsigned short* __restrict__ S,
                                                 const uint4* __restrict__ VbP,
                                                 const float* __restrict__ bm,
                                                 const float* __restrict__ ba,
                                                 const float* __restrict__ bs,
                                                 float* __restrict__ out) {
    __shared__ short8 vbsh[DC][2][64];  // 16 KB  A-frags
    __shared__ float  wshf[DC][64];     //  2 KB  W[d][h] f32
    __shared__ float  xsf[DC][128];     //  4 KB  x[d][b_local]
    __shared__ float  bshf[DC][16];     // 0.5 KB bias by m-row

    const int tid    = threadIdx.x;
    const int lane   = tid & 63;
    const int w      = tid >> 6;
    const int t      = blockIdx.y;
    const int bx     = blockIdx.x;
    const int dstart = 8 * t + 4;
    const int dvalid = D - dstart;       // 8, except 4 at t=127
    const int r      = lane & 15;        // n within tile (b)
    const int qq     = lane >> 4;        // quarter -> m-row group / k-slice

    // ---- stage chunk ----
    {
        {   // A-frags: dvalid*128 uint4 <= 1024
            const uint4* vsrc = VbP + (size_t)dstart * 128;
            uint4* vdst = (uint4*)vbsh;
#pragma unroll
            for (int q = 0; q < 4; ++q) {
                const int j = q * 256 + tid;
                if (j < dvalid * 128) vdst[j] = vsrc[j];
            }
        }
        {   // W: dvalid*32 dwords <= 256
            const unsigned* wsrc = (const unsigned*)(Wth + (size_t)dstart * H);
            if (tid < dvalid * 32) {
                const unsigned u = wsrc[tid];
                const int dl = tid >> 5, h = (tid & 31) * 2;
                wshf[dl][h]     = h2f_u((unsigned short)(u & 0xffff));
                wshf[dl][h + 1] = h2f_u((unsigned short)(u >> 16));
            }
        }
        {   // x: 128 rows x dvalid floats; thread j -> (row j>>1, part j&1)
            const int row = tid >> 1, part = tid & 1;
            if (part * 4 < dvalid) {
                float4 v = *(const float4*)(x + (size_t)(bx * 128 + row) * D + dstart + part * 4);
                xsf[part * 4 + 0][row] = v.x;
                xsf[part * 4 + 1][row] = v.y;
                xsf[part * 4 + 2][row] = v.z;
                xsf[part * 4 + 3][row] = v.w;
            }
        }
        {   // bias: thread -> (dl, m)
            if (tid < DC * 16) {
                const int dl = tid >> 4, m = tid & 15;
                const int d = dstart + dl;
                float v = 0.f;
                if (d < D) {
                    if (m < 3)                 v = bm[(size_t)d * 3 + m];
                    else if (m >= 4 && m < 7)  v = bs[(size_t)d * 3 + m - 4];
                    else if (m >= 8 && m < 11) v = ba[(size_t)d * 3 + m - 8];
                }
                bshf[dl][m] = v;
            }
        }
    }

    // ---- load f16 checkpoints into B-frag-layout state a[bt][ks][j] ----
    float a_[2][2][8];
#pragma unroll
    for (int bt = 0; bt < 2; ++bt) {
#pragma unroll
        for (int ks = 0; ks < 2; ++ks) {
            const unsigned short* sp =
                S + ((size_t)t * B + bx * 128 + w * 32 + bt * 16 + r) * H + ks * 32 + qq * 8;
            uint4 u = *(const uint4*)sp;
            a_[bt][ks][0] = h2f_u((unsigned short)(u.x & 0xffff));
            a_[bt][ks][1] = h2f_u((unsigned short)(u.x >> 16));
            a_[bt][ks][2] = h2f_u((unsigned short)(u.y & 0xffff));
            a_[bt][ks][3] = h2f_u((unsigned short)(u.y >> 16));
            a_[bt][ks][4] = h2f_u((unsigned short)(u.z & 0xffff));
            a_[bt][ks][5] = h2f_u((unsigned short)(u.z >> 16));
            a_[bt][ks][6] = h2f_u((unsigned short)(u.w & 0xffff));
            a_[bt][ks][7] = h2f_u((unsigned short)(u.w >> 16));
        }
    }
    __syncthreads();

    const int nq = (t == T - 1) ? 1 : 2;
    for (int qd = 0; qd < nq; ++qd) {
        float buf[2][12];
#pragma unroll
        for (int d4 = 0; d4 < 4; ++d4) {
            const int dl = qd * 4 + d4;

            // A-frags from LDS (ds_read_b128)
            short8 A0 = vbsh[dl][0][lane];
            short8 A1 = vbsh[dl][1][lane];

            // B-frags: relu + pack to bf16
            U8 bf[2][2];
#pragma unroll
            for (int bt = 0; bt < 2; ++bt)
#pragma unroll
                for (int ks = 0; ks < 2; ++ks)
#pragma unroll
                    for (int i = 0; i < 4; ++i)
                        bf[bt][ks].u[i] = cvtpk_bf16(fmaxf(a_[bt][ks][2 * i], 0.f),
                                                     fmaxf(a_[bt][ks][2 * i + 1], 0.f));

            f32x4 bias4 = ((const f32x4*)&bshf[dl][0])[qq];

            // 4 MFMA: 2 bt x 2 chained K-steps
            f32x4 acc[2];
#pragma unroll
            for (int bt = 0; bt < 2; ++bt) {
                acc[bt] = __builtin_amdgcn_mfma_f32_16x16x32_bf16(A0, bf[bt][0].s, bias4, 0, 0, 0);
                acc[bt] = __builtin_amdgcn_mfma_f32_16x16x32_bf16(A1, bf[bt][1].s, acc[bt], 0, 0, 0);
            }

            // epilogue per lane-quarter: q0 mean (raw), q1 std, q2 alpha, q3 idle
#pragma unroll
            for (int bt = 0; bt < 2; ++bt) {
                float z0 = acc[bt][0], z1 = acc[bt][1], z2 = acc[bt][2];
                float o0 = z0, o1 = z1, o2 = z2;
                if (qq == 1) {
                    o0 = 2.f * __builtin_amdgcn_rcpf(1.f + __expf(-z0)) + 0.6f;
                    o1 = 2.f * __builtin_amdgcn_rcpf(1.f + __expf(-z1)) + 0.6f;
                    o2 = 2.f * __builtin_amdgcn_rcpf(1.f + __expf(-z2)) + 0.6f;
                } else if (qq == 2) {
                    float mx = fmaxf(z0, fmaxf(z1, z2));
                    float e0 = __expf(z0 - mx);
                    float e1 = __expf(z1 - mx);
                    float e2 = __expf(z2 - mx);
                    float inv = __builtin_amdgcn_rcpf(e0 + e1 + e2);
                    o0 = e0 * inv; o1 = e1 * inv; o2 = e2 * inv;
                }
                buf[bt][d4 * 3 + 0] = o0;
                buf[bt][d4 * 3 + 1] = o1;
                buf[bt][d4 * 3 + 2] = o2;
            }

            // a-update: a[bt][ks][j] += x[b(bt)] * W[h(ks,qq,j)]
            float4 w0a = *(const float4*)&wshf[dl][qq * 8];
            float4 w0b = *(const float4*)&wshf[dl][qq * 8 + 4];
            float4 w1a = *(const float4*)&wshf[dl][32 + qq * 8];
            float4 w1b = *(const float4*)&wshf[dl][32 + qq * 8 + 4];
#pragma unroll
            for (int bt = 0; bt < 2; ++bt) {
                const float xv = xsf[dl][w * 32 + bt * 16 + r];
                a_[bt][0][0] = fmaf(xv, w0a.x, a_[bt][0][0]);
                a_[bt][0][1] = fmaf(xv, w0a.y, a_[bt][0][1]);
                a_[bt][0][2] = fmaf(xv, w0a.z, a_[bt][0][2]);
                a_[bt][0][3] = fmaf(xv, w0a.w, a_[bt][0][3]);
                a_[bt][0][4] = fmaf(xv, w0b.x, a_[bt][0][4]);
                a_[bt][0][5] = fmaf(xv, w0b.y, a_[bt][0][5]);
                a_[bt][0][6] = fmaf(xv, w0b.z, a_[bt][0][6]);
                a_[bt][0][7] = fmaf(xv, w0b.w, a_[bt][0][7]);
                a_[bt][1][0] = fmaf(xv, w1a.x, a_[bt][1][0]);
                a_[bt][1][1] = fmaf(xv, w1a.y, a_[bt][1][1]);
                a_[bt][1][2] = fmaf(xv, w1a.z, a_[bt][1][2]);
                a_[bt][1][3] = fmaf(xv, w1a.w, a_[bt][1][3]);
                a_[bt][1][4] = fmaf(xv, w1b.x, a_[bt][1][4]);
                a_[bt][1][5] = fmaf(xv, w1b.y, a_[bt][1][5]);
                a_[bt][1][6] = fmaf(xv, w1b.z, a_[bt][1][6]);
                a_[bt][1][7] = fmaf(xv, w1b.w, a_[bt][1][7]);
            }
        }

        // flush: 48B-aligned float4 runs; i0 = 8t + 4qd
        if (qq < 3) {
            float* ob = out + (size_t)qq * ((size_t)B * DOUT * 3);
            const size_t ioff = (size_t)(8 * t + 4 * qd) * 3;
#pragma unroll
            for (int bt = 0; bt < 2; ++bt) {
                float* p = ob + (size_t)(bx * 128 + w * 32 + bt * 16 + r) * (DOUT * 3) + ioff;
                *(float4*)(p + 0) = make_float4(buf[bt][0], buf[bt][1], buf[bt][2], buf[bt][3]);
                *(float4*)(p + 4) = make_float4(buf[bt][4], buf[bt][5], buf[bt][6], buf[bt][7]);
                *(float4*)(p + 8) = make_float4(buf[bt][8], buf[bt][9], buf[bt][10], buf[bt][11]);
            }
        }
    }
}

// ---------------------------------------------------------------------------
extern "C" void kernel_launch(void* const* d_in, const int* in_sizes, int n_in,
                              void* d_out, int out_size, void* d_ws, size_t ws_size,
                              hipStream_t stream) {
    const float* x  = (const float*)d_in[0];   // [B, D]
    const float* W  = (const float*)d_in[1];   // [H, D]
    const float* c  = (const float*)d_in[2];   // [1, H]
    const float* Vm = (const float*)d_in[3];   // [D, H, K]
    const float* Va = (const float*)d_in[4];   // [D, H, K]
    const float* Vs = (const float*)d_in[5];   // [D, H, K]
    const float* bm = (const float*)d_in[6];   // [D, K]
    const float* ba = (const float*)d_in[7];   // [D, K]
    const float* bs = (const float*)d_in[8];   // [D, K]
    float* out = (float*)d_out;

    float* wsf = (float*)d_ws;
    unsigned short* S = (unsigned short*)(wsf + WS_S);
    uint4* VbP = (uint4*)(wsf + WS_VB);
    unsigned short* Wth = (unsigned short*)(wsf + WS_WT);

    k_prep<<<dim3(256 + 16), dim3(256), 0, stream>>>(Vm, Va, Vs, W, VbP, Wth);
    k_prefix<<<dim3(B / 8), dim3(512), 0, stream>>>(x, W, c, S);
    k_main<<<dim3(B / 128, T), dim3(256), 0, stream>>>(x, Wth, S, VbP, bm, ba, bs, out);
}